// Round 8
// baseline (2403.152 us; speedup 1.0000x reference)
//
#include <hip/hip_runtime.h>

// LIF, Round 8 — THREE kernels total so the profile attributes time:
//   w3_prep:  W fp32 -> 3 bf16 planes (hi/mid/lo), K-chunk-major   (~3 us)
//   xs_gemm:  xs = spikes @ W^T, full T at once (M=262144,N=512,K=512)
//   lif_scan: 131072 independent LIF chains over all 1024 steps
//
// R7 post-mortem: 17 dispatches hid the hot spot (top-5 = harness's 2 GiB
// ws-poison fills, ~480 us/iter harness floor in EVERY round's dur_us).
// Also consecutive blockIdx -> different XCDs meant 4x A re-fetch.
// R8: one big GEMM, N-split 2, XCD-pairing swizzle (A-tile partners get
// bids differing by 8 -> same XCD L2 -> A fetched from HBM once).
//
// Numerics: identical to R7's passing path (3x bf16 W-split, spikes exact
// via bf16 truncation, fp32 accumulate; absmax 3.9e-3 vs 6.2e-2 threshold).

typedef __attribute__((ext_vector_type(8))) short short8;   // 8 x bf16
typedef __attribute__((ext_vector_type(4))) float floatx4;

#define T_STEPS 1024
#define B_DIM   256
#define F_DIM   512
#define BF      (B_DIM * F_DIM)
#define M_ALL   (T_STEPS * B_DIM)     // 262144
#define MT      128
#define NT      256
#define ROWP    72                    // padded LDS row, ushorts (144 B = 9 granules)

// ws layout (bytes); harness ws is 2 GiB (proven by its 2.147e9-byte fills)
#define W3_BYTES (3 * 8 * 512 * 64 * 2)           // 1,572,864
#define XS_OFF   ((size_t)W3_BYTES)
#define WS_NEED  (XS_OFF + (size_t)M_ALL * F_DIM * 4)   // ~538 MB

static __device__ __forceinline__ unsigned short f2bf_rne(float f) {
    unsigned u = __float_as_uint(f);
    return (unsigned short)((u + 0x7FFFu + ((u >> 16) & 1u)) >> 16);
}
static __device__ __forceinline__ float bf2f(unsigned short h) {
    return __uint_as_float(((unsigned)h) << 16);
}

// ---------------------------------------------------------------- w3_prep
// w3[((p*8+ks)*512 + g)*64 + j] = split_p(W[g][ks*64+j])
__global__ void w3_prep(const float* __restrict__ W,
                        unsigned short* __restrict__ w3)
{
    const int g = blockIdx.x;        // 512
    const int j = threadIdx.x;       // 64
    for (int ks = 0; ks < 8; ++ks) {
        float w = W[g * 512 + ks * 64 + j];
        unsigned short h = f2bf_rne(w);
        float r1 = w - bf2f(h);
        unsigned short m = f2bf_rne(r1);
        float r2 = r1 - bf2f(m);
        unsigned short l = f2bf_rne(r2);
        w3[((size_t)(0 * 8 + ks) * 512 + g) * 64 + j] = h;
        w3[((size_t)(1 * 8 + ks) * 512 + g) * 64 + j] = m;
        w3[((size_t)(2 * 8 + ks) * 512 + g) * 64 + j] = l;
    }
}

// ---------------------------------------------------------------- xs_gemm
// C[m,g] = sum_f A[m,f]*W[g,f], M=262144, N=512 (2 n-tiles of 256), K=512.
// 4096 blocks x 512 thr (8 waves of 64x64). BK=64, 8 K-steps, software-
// pipelined reg-staging (R7-proven inner). LDS rows padded to 72 ushorts.
// Swizzle: xcd=bid&7, nt=(bid>>3)&1, mt=(bid>>4)*8+xcd -> the two blocks
// sharing an A-tile (nt=0/1) differ by 8 in bid: same XCD, co-dispatched.
__global__ __launch_bounds__(512, 2)
void xs_gemm(const float* __restrict__ A,          // spikes [M_ALL][512]
             const unsigned short* __restrict__ w3,
             float* __restrict__ xs)               // [M_ALL][512]
{
    __shared__ unsigned short sA[MT * ROWP];       // 18432 B
    __shared__ unsigned short sB[3 * NT * ROWP];   // 110592 B

    const int tid  = threadIdx.x;
    const unsigned lane = tid & 63u;
    const int w    = tid >> 6;                 // 0..7
    const int bid  = blockIdx.x;
    const int xcd  = bid & 7;
    const int nt   = (bid >> 3) & 1;
    const int mt   = (bid >> 4) * 8 + xcd;     // 0..2047
    const int m0   = mt * MT;
    const int g0   = nt * NT;
    const int wm   = w & 1;                    // m-half
    const int wn   = w >> 1;                   // n-quarter
    const int mh   = wm * 64;
    const int nh   = wn * 64;
    const int mrow = lane & 15;
    const int kq   = lane >> 4;

    floatx4 acc[4][4];
    #pragma unroll
    for (int mi = 0; mi < 4; ++mi)
        #pragma unroll
        for (int ni = 0; ni < 4; ++ni)
            acc[mi][ni] = (floatx4){0.f, 0.f, 0.f, 0.f};

    // A staging role: 32 row-groups x 16 thr; rows ar+32p, float4 col af
    const int ar = tid >> 4;       // 0..31
    const int af = tid & 15;       // 0..15

    float4 aA[4];
    uint4  bB[12];

    auto loadA = [&](int ks) {
        #pragma unroll
        for (int p = 0; p < 4; ++p)
            aA[p] = *(const float4*)(A + (size_t)(m0 + ar + 32 * p) * 512
                                       + ks * 64 + af * 4);
    };
    auto loadB = [&](int ks) {
        #pragma unroll
        for (int s = 0; s < 12; ++s) {
            const int q  = tid + 512 * s;      // 0..6143 (uint4 index)
            const int p  = q >> 11;            // plane 0..2
            const int qq = q & 2047;
            const int gr = qq >> 3;            // 0..255
            const int ci = qq & 7;             // 16B column
            bB[s] = *(const uint4*)(w3 + ((size_t)(p * 8 + ks) * 512 + g0 + gr) * 64
                                       + ci * 8);
        }
    };
    auto writeA = [&]() {
        #pragma unroll
        for (int p = 0; p < 4; ++p) {
            unsigned u0 = __float_as_uint(aA[p].x);
            unsigned u1 = __float_as_uint(aA[p].y);
            unsigned u2 = __float_as_uint(aA[p].z);
            unsigned u3 = __float_as_uint(aA[p].w);
            uint2 d;   // spikes {0,1}: bf16 truncation exact
            d.x = (u0 >> 16) | (u1 & 0xFFFF0000u);
            d.y = (u2 >> 16) | (u3 & 0xFFFF0000u);
            *(uint2*)&sA[(ar + 32 * p) * ROWP + af * 4] = d;
        }
    };
    auto writeB = [&]() {
        #pragma unroll
        for (int s = 0; s < 12; ++s) {
            const int q  = tid + 512 * s;
            const int p  = q >> 11;
            const int qq = q & 2047;
            const int gr = qq >> 3;
            const int ci = qq & 7;
            *(uint4*)&sB[p * (NT * ROWP) + gr * ROWP + ci * 8] = bB[s];
        }
    };

    loadA(0); loadB(0);
    for (int ks = 0; ks < 8; ++ks) {
        writeA(); writeB();
        __syncthreads();                        // tile ks staged
        if (ks < 7) { loadA(ks + 1); loadB(ks + 1); }   // hide under MFMA

        #pragma unroll
        for (int kc = 0; kc < 2; ++kc) {
            short8 afr[4];
            #pragma unroll
            for (int mi = 0; mi < 4; ++mi)
                afr[mi] = *(const short8*)(sA + (mh + mi * 16 + mrow) * ROWP
                                              + kc * 32 + kq * 8);
            #pragma unroll
            for (int p = 0; p < 3; ++p) {
                short8 bfr[4];
                #pragma unroll
                for (int ni = 0; ni < 4; ++ni)
                    bfr[ni] = *(const short8*)(sB + p * (NT * ROWP)
                                                  + (nh + ni * 16 + mrow) * ROWP
                                                  + kc * 32 + kq * 8);
                #pragma unroll
                for (int mi = 0; mi < 4; ++mi)
                    #pragma unroll
                    for (int ni = 0; ni < 4; ++ni)
                        acc[mi][ni] = __builtin_amdgcn_mfma_f32_16x16x32_bf16(
                            afr[mi], bfr[ni], acc[mi][ni], 0, 0, 0);
            }
        }
        __syncthreads();                        // reads done before overwrite
    }

    // epilogue: C-layout col = lane&15 (g), row = kq*4+r (m)
    #pragma unroll
    for (int mi = 0; mi < 4; ++mi)
        #pragma unroll
        for (int ni = 0; ni < 4; ++ni) {
            const int gg = g0 + nh + ni * 16 + mrow;
            const int mm = m0 + mh + mi * 16 + kq * 4;
            #pragma unroll
            for (int r = 0; r < 4; ++r)
                xs[(size_t)(mm + r) * 512 + gg] = acc[mi][ni][r];
        }
}

// ---------------------------------------------------------------- lif_scan
// 131072 independent chains over all T=1024 steps; 8-deep register prefetch.
__global__ __launch_bounds__(256)
void lif_scan(const float* __restrict__ xs, float* __restrict__ out)
{
    const int n = blockIdx.x * 256 + threadIdx.x;
    float v = 0.f, cu = 0.f, zf = 0.f;

    float buf[8];
    #pragma unroll
    for (int j = 0; j < 8; ++j) buf[j] = xs[(size_t)j * BF + n];

    #pragma unroll 8
    for (int t = 0; t < T_STEPS; ++t) {
        float x    = buf[t & 7];
        float vdec = v + 0.1f * ((0.0f - v) + cu);   // DT*TAU_MEM_INV = 0.1
        float idec = cu - 0.2f * cu;                  // DT*TAU_SYN_INV = 0.2
        bool  spk  = (vdec - 1.0f) > 0.0f;            // heaviside
        zf = spk ? 1.0f : 0.0f;
        v  = spk ? 0.0f : vdec;                       // V_RESET = 0
        cu = idec + x;
        if (t + 8 < T_STEPS) buf[t & 7] = xs[(size_t)(t + 8) * BF + n];
    }

    out[n]          = zf;
    out[BF + n]     = v;
    out[2 * BF + n] = cu;
}

// ========================================================== launch
extern "C" void kernel_launch(void* const* d_in, const int* in_sizes, int n_in,
                              void* d_out, int out_size, void* d_ws, size_t ws_size,
                              hipStream_t stream)
{
    const float* spikes = (const float*)d_in[0];   // [T,B,F] fp32
    const float* W      = (const float*)d_in[1];   // [F,F]   fp32
    float* out          = (float*)d_out;           // [3,B,F] fp32

    unsigned short* w3 = (unsigned short*)d_ws;
    float* xs          = (float*)((char*)d_ws + XS_OFF);

    w3_prep<<<dim3(512), dim3(64), 0, stream>>>(W, w3);
    xs_gemm<<<dim3(4096), dim3(512), 0, stream>>>(spikes, w3, xs);
    lif_scan<<<dim3(512), dim3(256), 0, stream>>>(xs, out);
}